// Round 7
// baseline (40.973 us; speedup 1.0000x reference)
//
#include <hip/hip_runtime.h>
#include <math.h>

#define NG 512
#define NV 76800
#define FD 32
#define CAP 64
// voxel grid 80x80x12; tiles 8x8x6 -> 10x10x2 = 200 blocks
// block = 768 threads = 12 waves (3/SIMD): 2 survivor-slices x 384 voxels
// R6 = measurement round: identical R5 kernel launched 4x (3x -> d_ws, 1x -> d_out)
// to separate fixed (launch/measurement) cost from per-kernel cost.

__global__ __launch_bounds__(768, 3) void voxelize_kernel(
    const float* __restrict__ means, const float* __restrict__ opac,
    const float* __restrict__ cov, const float* __restrict__ feats,
    float* __restrict__ out)
{
    // LDS pool: phase A = records (~12 KB), phase B = partials [33][384] (50.7 KB)
    __shared__ float pool[33 * 384];
    __shared__ int   s_n[CAP];
    __shared__ int   s_cnt;

    float4* gp = (float4*)pool;          // [CAP+4] mx,my,mz,r2
    float4* gq = gp + (CAP + 4);         // [CAP+4] i00,i01,i02,i11
    float4* gt = gq + (CAP + 4);         // [CAP+4] i12,i22,op,-
    float*  gf = (float*)(gt + (CAP + 4)); // [CAP+4][FD]

    const int tid  = threadIdx.x;
    const int lane = tid & 63;

    const int b   = blockIdx.x;
    const int tiz = b % 2;
    const int tiy = (b / 2) % 10;
    const int tix = b / 20;

    // tile voxel-center AABB (world units)
    const float xlo = (tix * 8 + 0.5f) * 0.5f - 20.f, xhi = xlo + 3.5f;
    const float ylo = (tiy * 8 + 0.5f) * 0.5f - 20.f, yhi = ylo + 3.5f;
    const float zlo = (tiz * 6 + 0.5f) * 0.5f -  2.f, zhi = zlo + 2.5f;

    if (tid == 0) s_cnt = 0;
    __syncthreads();

    // ---- phase 1: gate 512 gaussians (threads 0..511), compact survivors
    if (tid < NG) {
        const int n = tid;
        const float a = cov[n*9+0], bb = cov[n*9+1], c = cov[n*9+2];
        const float d = cov[n*9+4], e  = cov[n*9+5], f = cov[n*9+8];
        const float sx = sqrtf(a), sy = sqrtf(d), sz = sqrtf(f);
        const float mx = means[n*3+0], my = means[n*3+1], mz = means[n*3+2];
        const float op = opac[n];
        const bool keep =
            (mx + 3.f*sx > -20.f) && (my + 3.f*sy > -20.f) && (mz + 3.f*sz > -2.f) &&
            (mx - 3.f*sx <  20.f) && (my - 3.f*sy <  20.f) && (mz - 3.f*sz <  4.4f) &&
            (op > 1e-4f);
        const float smax = fmaxf(sx, fmaxf(sy, sz));
        const float r2 = 9.f * smax * smax;
        const float cx = fminf(fmaxf(mx, xlo), xhi) - mx;
        const float cy = fminf(fmaxf(my, ylo), yhi) - my;
        const float cz = fminf(fmaxf(mz, zlo), zhi) - mz;
        const float d2t = cx*cx + cy*cy + cz*cz;
        const bool pred = keep && (d2t < r2);

        const unsigned long long m = __ballot(pred);
        int wofs = 0;
        if (lane == 0) wofs = atomicAdd(&s_cnt, (int)__popcll(m));
        wofs = __shfl(wofs, 0);
        const int pos = wofs + (int)__popcll(m & ((1ull << lane) - 1ull));
        if (pred && pos < CAP) {
            const float det = a*(d*f - e*e) - bb*(bb*f - c*e) + c*(bb*e - c*d);
            const float id = 1.f / det;
            gp[pos] = make_float4(mx, my, mz, r2);
            gq[pos] = make_float4((d*f - e*e) * id,
                                  (c*e - bb*f) * id,
                                  (bb*e - c*d) * id,
                                  (a*f - c*c) * id);
            gt[pos] = make_float4((bb*c - a*e) * id,
                                  (a*d - bb*bb) * id,
                                  op, 0.f);
            s_n[pos] = n;
        }
    }
    __syncthreads();
    const int ks = (s_cnt < CAP) ? s_cnt : CAP;

    // ---- pad 4 dummy records after the list (prefetch reads them branch-free)
    if (tid < 4) {
        gp[ks + tid] = make_float4(1e9f, 1e9f, 1e9f, -1.f);
        gq[ks + tid] = make_float4(0.f, 0.f, 0.f, 0.f);
        gt[ks + tid] = make_float4(0.f, 0.f, 0.f, 0.f);
    }
    // zero the 4 dummy feature rows (128 floats = 32 float4)
    if (tid < 32) ((float4*)(gf + ks * FD))[tid] = make_float4(0.f, 0.f, 0.f, 0.f);

    // ---- phase 1.5: stage survivor feature rows into LDS
    for (int it = tid; it < ks * 8; it += 768) {
        const int s = it >> 3, j = it & 7;
        ((float4*)(gf + s * FD))[j] = ((const float4*)(feats + (size_t)s_n[s] * FD))[j];
    }
    __syncthreads();

    // ---- phase 2: branchless, sliced (2 slices), 1-ahead prefetched
    const int sl = tid / 384;           // survivor slice 0/1 (wave-uniform: 6 waves each)
    const int u  = tid - sl * 384;      // voxel index within tile
    const int lz = u % 6;
    const int ly = (u / 6) % 8;
    const int lx = u / 48;
    const int ix = tix * 8 + lx;
    const int iy = tiy * 8 + ly;
    const int iz = tiz * 6 + lz;
    const float x = (ix + 0.5f) * 0.5f - 20.f;
    const float y = (iy + 0.5f) * 0.5f - 20.f;
    const float z = (iz + 0.5f) * 0.5f -  2.f;

    float dens = 0.f;
    float4 acc[8];
    #pragma unroll
    for (int j = 0; j < 8; ++j) acc[j] = make_float4(0.f, 0.f, 0.f, 0.f);

    // prologue: load slice's first record (dummy-safe)
    float4 p = gp[sl], q = gq[sl], t = gt[sl];
    float4 f[8];
    #pragma unroll
    for (int j = 0; j < 8; ++j) f[j] = ((float4*)(gf + sl * FD))[j];

    for (int i = sl; i < ks; i += 2) {
        const int ip = i + 2;           // <= ks+1: dummy records exist
        const float4 pn = gp[ip], qn = gq[ip], tn = gt[ip];
        float4 fn[8];
        #pragma unroll
        for (int j = 0; j < 8; ++j) fn[j] = ((float4*)(gf + ip * FD))[j];

        const float dx = p.x - x, dy = p.y - y, dz = p.z - z;
        const float d2 = dx*dx + dy*dy + dz*dz;
        const float maha = q.x*dx*dx + q.w*dy*dy + t.y*dz*dz
                         + 2.f*(q.y*dx*dy + q.z*dx*dz + t.x*dy*dz);
        float w = t.z * __expf(-0.5f * maha);
        w = (d2 < p.w) ? w : 0.f;       // select after exp: no 0*inf
        dens += w;
        #pragma unroll
        for (int j = 0; j < 8; ++j) {
            acc[j].x += w * f[j].x; acc[j].y += w * f[j].y;
            acc[j].z += w * f[j].z; acc[j].w += w * f[j].w;
        }
        p = pn; q = qn; t = tn;
        #pragma unroll
        for (int j = 0; j < 8; ++j) f[j] = fn[j];
    }

    // ---- phase 3: cross-slice reduction via LDS partials [33][384]
    __syncthreads();                    // records dead; pool reusable
    if (sl == 1) {
        pool[u] = dens;
        #pragma unroll
        for (int j = 0; j < 8; ++j) {
            pool[(1 + j*4 + 0) * 384 + u] = acc[j].x;
            pool[(1 + j*4 + 1) * 384 + u] = acc[j].y;
            pool[(1 + j*4 + 2) * 384 + u] = acc[j].z;
            pool[(1 + j*4 + 3) * 384 + u] = acc[j].w;
        }
    }
    __syncthreads();
    if (sl == 0) {
        dens += pool[u];
        #pragma unroll
        for (int j = 0; j < 8; ++j) {
            acc[j].x += pool[(1 + j*4 + 0) * 384 + u];
            acc[j].y += pool[(1 + j*4 + 1) * 384 + u];
            acc[j].z += pool[(1 + j*4 + 2) * 384 + u];
            acc[j].w += pool[(1 + j*4 + 3) * 384 + u];
        }
        const int v = (ix * 80 + iy) * 12 + iz;
        out[v] = dens;
        const float inv = 1.f / fmaxf(dens, 1e-6f);
        float4* fo = (float4*)(out + NV + (size_t)v * FD);
        #pragma unroll
        for (int j = 0; j < 8; ++j) {
            float4 rr;
            rr.x = acc[j].x * inv; rr.y = acc[j].y * inv;
            rr.z = acc[j].z * inv; rr.w = acc[j].w * inv;
            fo[j] = rr;
        }
    }
}

extern "C" void kernel_launch(void* const* d_in, const int* in_sizes, int n_in,
                              void* d_out, int out_size, void* d_ws, size_t ws_size,
                              hipStream_t stream) {
    const float* means = (const float*)d_in[0];
    const float* opac  = (const float*)d_in[1];
    const float* cov   = (const float*)d_in[2];
    const float* feats = (const float*)d_in[3];
    float* out = (float*)d_out;

    // Slope experiment: 3 extra identical launches into scratch (if it fits),
    // then the real launch into d_out. dur_us = F + 4*t_k; R5 gave F + t_k = 13.92.
    const size_t need = (size_t)NV * (FD + 1) * sizeof(float);
    float* tmp = (ws_size >= need) ? (float*)d_ws : out;
    voxelize_kernel<<<200, 768, 0, stream>>>(means, opac, cov, feats, tmp);
    voxelize_kernel<<<200, 768, 0, stream>>>(means, opac, cov, feats, tmp);
    voxelize_kernel<<<200, 768, 0, stream>>>(means, opac, cov, feats, tmp);
    voxelize_kernel<<<200, 768, 0, stream>>>(means, opac, cov, feats, out);
}

// Round 8
// 14.064 us; speedup vs baseline: 2.9134x; 2.9134x over previous
//
#include <hip/hip_runtime.h>
#include <math.h>

#define NG 512
#define NV 76800
#define FD 32
#define CAP 64
// voxel grid 80x80x12; tiles 10x10x3 -> 8x8x4 = 256 blocks (1 per CU), 320 threads

__global__ __launch_bounds__(320) void voxelize_kernel(
    const float* __restrict__ means, const float* __restrict__ opac,
    const float* __restrict__ cov, const float* __restrict__ feats,
    float* __restrict__ out)
{
    __shared__ float4 gp[CAP];   // mx,my,mz,r2
    __shared__ float4 gq[CAP];   // i00,i01,i02,i11
    __shared__ float4 gt[CAP];   // i12,i22,op,-
    __shared__ int    s_n[CAP];
    __shared__ int    s_cnt;

    const int tid  = threadIdx.x;
    const int lane = tid & 63;

    const int b   = blockIdx.x;
    const int tiz = b & 3;           // 0..3
    const int tiy = (b >> 2) & 7;    // 0..7
    const int tix = b >> 5;          // 0..7

    // tile voxel-center AABB (world units): 10x10x3 voxels
    const float xlo = (tix * 10 + 0.5f) * 0.5f - 20.f, xhi = xlo + 4.5f;
    const float ylo = (tiy * 10 + 0.5f) * 0.5f - 20.f, yhi = ylo + 4.5f;
    const float zlo = (tiz * 3  + 0.5f) * 0.5f -  2.f, zhi = zlo + 1.0f;

    if (tid == 0) s_cnt = 0;
    __syncthreads();

    // ---- phase 1: gate 512 gaussians (2 rounds over 320 threads), compact survivors
    #pragma unroll
    for (int r = 0; r < 2; ++r) {
        const int n = r * 320 + tid;
        if (n < NG) {
            const float a = cov[n*9+0], bb = cov[n*9+1], c = cov[n*9+2];
            const float d = cov[n*9+4], e  = cov[n*9+5], f = cov[n*9+8];
            const float sx = sqrtf(a), sy = sqrtf(d), sz = sqrtf(f);
            const float mx = means[n*3+0], my = means[n*3+1], mz = means[n*3+2];
            const float op = opac[n];
            const bool keep =
                (mx + 3.f*sx > -20.f) && (my + 3.f*sy > -20.f) && (mz + 3.f*sz > -2.f) &&
                (mx - 3.f*sx <  20.f) && (my - 3.f*sy <  20.f) && (mz - 3.f*sz <  4.4f) &&
                (op > 1e-4f);
            const float smax = fmaxf(sx, fmaxf(sy, sz));
            const float r2 = 9.f * smax * smax;
            const float cx = fminf(fmaxf(mx, xlo), xhi) - mx;
            const float cy = fminf(fmaxf(my, ylo), yhi) - my;
            const float cz = fminf(fmaxf(mz, zlo), zhi) - mz;
            const float d2t = cx*cx + cy*cy + cz*cz;
            const bool pred = keep && (d2t < r2);

            const unsigned long long m = __ballot(pred);
            int wofs = 0;
            if (lane == 0) wofs = atomicAdd(&s_cnt, (int)__popcll(m));
            wofs = __shfl(wofs, 0);
            const int pos = wofs + (int)__popcll(m & ((1ull << lane) - 1ull));
            if (pred && pos < CAP) {
                const float det = a*(d*f - e*e) - bb*(bb*f - c*e) + c*(bb*e - c*d);
                const float id = 1.f / det;
                gp[pos] = make_float4(mx, my, mz, r2);
                gq[pos] = make_float4((d*f - e*e) * id,   // i00
                                      (c*e - bb*f) * id,  // i01
                                      (bb*e - c*d) * id,  // i02
                                      (a*f - c*c) * id);  // i11
                gt[pos] = make_float4((bb*c - a*e) * id,  // i12
                                      (a*d - bb*bb) * id, // i22
                                      op, 0.f);
                s_n[pos] = n;
            }
        }
    }
    __syncthreads();
    const int ks = (s_cnt < CAP) ? s_cnt : CAP;

    // ---- phase 2: voxel threads (u < 300); no barriers below
    const int u = tid;
    if (u < 300) {
        const int lz = u % 3;
        const int ly = (u / 3) % 10;
        const int lx = u / 30;
        const int ix = tix * 10 + lx;
        const int iy = tiy * 10 + ly;
        const int iz = tiz * 3  + lz;
        const float x = (ix + 0.5f) * 0.5f - 20.f;
        const float y = (iy + 0.5f) * 0.5f - 20.f;
        const float z = (iz + 0.5f) * 0.5f -  2.f;

        // pass A: branchless gate walk -> per-lane hit bitmask (broadcast LDS reads)
        unsigned long long hm = 0ull;
        for (int i = 0; i < ks; ++i) {
            const float4 p = gp[i];
            const float dx = p.x - x, dy = p.y - y, dz = p.z - z;
            const float d2 = dx*dx + dy*dy + dz*dz;
            hm |= (d2 < p.w) ? (1ull << i) : 0ull;
        }

        // pass B: per-lane walk of set bits only (~1-3 hits)
        float dens = 0.f;
        float4 acc[8];
        #pragma unroll
        for (int j = 0; j < 8; ++j) acc[j] = make_float4(0.f, 0.f, 0.f, 0.f);

        while (hm) {
            const int i = (int)__builtin_ctzll(hm);
            hm &= hm - 1ull;
            const float4 p = gp[i];
            const float4 q = gq[i];
            const float4 t = gt[i];
            const float dx = p.x - x, dy = p.y - y, dz = p.z - z;
            const float maha = q.x*dx*dx + q.w*dy*dy + t.y*dz*dz
                             + 2.f*(q.y*dx*dy + q.z*dx*dz + t.x*dy*dz);
            const float w = t.z * __expf(-0.5f * maha);
            dens += w;
            const float4* fp = (const float4*)(feats + (size_t)s_n[i] * FD);
            #pragma unroll
            for (int j = 0; j < 8; ++j) {
                const float4 f4 = fp[j];
                acc[j].x += w * f4.x; acc[j].y += w * f4.y;
                acc[j].z += w * f4.z; acc[j].w += w * f4.w;
            }
        }

        const int v = (ix * 80 + iy) * 12 + iz;
        out[v] = dens;
        const float inv = 1.f / fmaxf(dens, 1e-6f);
        float4* fo = (float4*)(out + NV + (size_t)v * FD);
        #pragma unroll
        for (int j = 0; j < 8; ++j) {
            float4 rr;
            rr.x = acc[j].x * inv; rr.y = acc[j].y * inv;
            rr.z = acc[j].z * inv; rr.w = acc[j].w * inv;
            fo[j] = rr;
        }
    }
}

extern "C" void kernel_launch(void* const* d_in, const int* in_sizes, int n_in,
                              void* d_out, int out_size, void* d_ws, size_t ws_size,
                              hipStream_t stream) {
    const float* means = (const float*)d_in[0];
    const float* opac  = (const float*)d_in[1];
    const float* cov   = (const float*)d_in[2];
    const float* feats = (const float*)d_in[3];
    float* out = (float*)d_out;
    voxelize_kernel<<<256, 320, 0, stream>>>(means, opac, cov, feats, out);
}